// Round 1
// baseline (84.158 us; speedup 1.0000x reference)
//
#include <hip/hip_runtime.h>

// 4-qubit, 3-layer circuit, B = bsz*4 circuits, one thread per circuit.
// d_ws layout: per layer l (l=0..2): ws[l*32 + i]    = 0.25*cos(ang_l(i))
//                                    ws[l*32 + 16+i] = 0.25*sin(ang_l(i))
// (the 0.25 folds each H-layer's (1/sqrt2)^4 normalization into the diagonal)

__global__ void precompute_phases(const float* __restrict__ weights,
                                  float* __restrict__ ws) {
    int t = threadIdx.x;
    if (t < 48) {
        int l = t >> 4;
        int idx = t & 15;
        float ang = 0.f;
        #pragma unroll
        for (int i = 0; i < 4; ++i) {
            int cb = (idx >> (3 - i)) & 1;                 // control = wire i
            int tb = (idx >> (3 - ((i + 1) & 3))) & 1;     // target  = wire (i+1)%4
            float phi = weights[l * 4 + i];
            if (cb) ang += (tb ? 0.5f : -0.5f) * phi;
        }
        ws[l * 32 + idx]      = 0.25f * cosf(ang);
        ws[l * 32 + 16 + idx] = 0.25f * sinf(ang);
    }
}

__device__ __forceinline__ void bfly(float v[16], int m) {
    #pragma unroll
    for (int i = 0; i < 16; ++i) {
        if (!(i & m)) {
            int j = i | m;
            float a = v[i], b = v[j];
            v[i] = a + b;
            v[j] = a - b;
        }
    }
}

__global__ __launch_bounds__(256) void qcircuit_kernel(
    const float* __restrict__ x,
    const float* __restrict__ lin_w,
    const float* __restrict__ lin_b,
    const float* __restrict__ ph,
    float* __restrict__ out,
    int nthreads)
{
    int t = blockIdx.x * blockDim.x + threadIdx.x;
    if (t >= nthreads) return;
    int b = t >> 2;
    int s = t & 3;

    // angle gather: xv = x.reshape(b,2,2,2,2).transpose(0,1,3,2,4) → circuit s, angle a
    const float* xr = x + (size_t)b * 16;
    int base = ((s >> 1) << 3) + ((s & 1) << 1);
    float2 q0 = *(const float2*)(xr + base);       // angles a=0,1
    float2 q1 = *(const float2*)(xr + base + 4);   // angles a=2,3
    float th0 = q0.x, th1 = q0.y, th2 = q1.x, th3 = q1.y;

    float c0 = __cosf(0.5f * th0), s0 = __sinf(0.5f * th0);
    float c1 = __cosf(0.5f * th1), s1 = __sinf(0.5f * th1);
    float c2 = __cosf(0.5f * th2), s2 = __sinf(0.5f * th2);
    float c3 = __cosf(0.5f * th3), s3 = __sinf(0.5f * th3);

    // product-state amplitudes: amp[idx] = w01[idx>>2] * w23[idx&3]
    float w01[4] = {c0 * c1, c0 * s1, s0 * c1, s0 * s1};
    float w23[4] = {c2 * c3, c2 * s3, s2 * c3, s2 * s3};

    float re[16], im[16];

    // layer 0: diagonal phase on the (real) product state
    #pragma unroll
    for (int i = 0; i < 16; ++i) {
        float a = w01[i >> 2] * w23[i & 3];
        re[i] = a * ph[i];
        im[i] = a * ph[16 + i];
    }
    bfly(re, 8); bfly(re, 4); bfly(re, 2); bfly(re, 1);
    bfly(im, 8); bfly(im, 4); bfly(im, 2); bfly(im, 1);

    // layers 1,2: complex diagonal, then H⊗4 butterfly
    #pragma unroll
    for (int l = 1; l < 3; ++l) {
        const float* pc = ph + l * 32;
        #pragma unroll
        for (int i = 0; i < 16; ++i) {
            float dc = pc[i], ds = pc[16 + i];
            float r = re[i] * dc - im[i] * ds;
            float m = re[i] * ds + im[i] * dc;
            re[i] = r; im[i] = m;
        }
        bfly(re, 8); bfly(re, 4); bfly(re, 2); bfly(re, 1);
        bfly(im, 8); bfly(im, 4); bfly(im, 2); bfly(im, 1);
    }

    // probabilities → Z expectations (wire w ↔ bit (3-w))
    float z0 = 0.f, z1 = 0.f, z2 = 0.f, z3 = 0.f;
    #pragma unroll
    for (int i = 0; i < 16; ++i) {
        float p = re[i] * re[i] + im[i] * im[i];
        z0 += (i & 8) ? -p : p;
        z1 += (i & 4) ? -p : p;
        z2 += (i & 2) ? -p : p;
        z3 += (i & 1) ? -p : p;
    }

    // partial logits: feature block j = s*4 + w
    float4 wa = *(const float4*)(lin_w + s * 4);
    float4 wb = *(const float4*)(lin_w + 16 + s * 4);
    float l0 = z0 * wa.x + z1 * wa.y + z2 * wa.z + z3 * wa.w;
    float l1 = z0 * wb.x + z1 * wb.y + z2 * wb.z + z3 * wb.w;

    // reduce across the 4 lanes of this batch row
    l0 += __shfl_xor(l0, 1); l0 += __shfl_xor(l0, 2);
    l1 += __shfl_xor(l1, 1); l1 += __shfl_xor(l1, 2);

    if (s == 0) {
        l0 += lin_b[0];
        l1 += lin_b[1];
        float m = fmaxf(l0, l1);
        float e0 = __expf(l0 - m), e1 = __expf(l1 - m);
        float inv = 1.f / (e0 + e1);
        *(float2*)(out + (size_t)b * 2) = make_float2(e0 * inv, e1 * inv);
    }
}

extern "C" void kernel_launch(void* const* d_in, const int* in_sizes, int n_in,
                              void* d_out, int out_size, void* d_ws, size_t ws_size,
                              hipStream_t stream) {
    const float* x       = (const float*)d_in[0];
    const float* weights = (const float*)d_in[1];
    const float* lin_w   = (const float*)d_in[2];
    const float* lin_b   = (const float*)d_in[3];
    float* out = (float*)d_out;
    float* ws  = (float*)d_ws;

    int bsz = in_sizes[0] / 16;
    int nthreads = bsz * 4;  // one thread per sub-circuit

    precompute_phases<<<1, 64, 0, stream>>>(weights, ws);

    int block = 256;
    int grid = (nthreads + block - 1) / block;
    qcircuit_kernel<<<grid, block, 0, stream>>>(x, lin_w, lin_b, ws, out, nthreads);
}

// Round 2
// 81.634 us; speedup vs baseline: 1.0309x; 1.0309x over previous
//
#include <hip/hip_runtime.h>

// 4-qubit, 3-layer circuit, one thread per sub-circuit (bsz*4 threads).
//
// Algebra: state after RY's is a real product state. Layers are
// (diag phase)·(H⊗4). The FINAL layer is folded away analytically:
//   z_w = sum_{j:(j&m)=0} 2*Re( d_j conj(d_{j^m}) * h_j conj(h_{j^m}) )
// where h = state after layer-1 butterfly, d = layer-2 phases, m = 8>>w.
// The 2cos/2sin of the phase differences are batch-uniform -> precomputed.
//
// d_ws layout (floats):
//   [0..31]   layer0: 0.25*cos(a0[i]) (16), 0.25*sin(a0[i]) (16)
//   [32..63]  layer1: same
//   [64..127] C table: for w=0..3, p=0..7: {2*cos(dA), 2*sin(dA)}
//             dA = a2[j] - a2[j|m], j = p-th index with bit m clear (ascending)

__device__ __forceinline__ float layer_angle(const float* __restrict__ w,
                                             int l, int idx) {
    float ang = 0.f;
    #pragma unroll
    for (int i = 0; i < 4; ++i) {
        int cb = (idx >> (3 - i)) & 1;                 // control = wire i
        int tb = (idx >> (3 - ((i + 1) & 3))) & 1;     // target  = wire (i+1)%4
        if (cb) ang += (tb ? 0.5f : -0.5f) * w[l * 4 + i];
    }
    return ang;
}

__global__ void precompute_tables(const float* __restrict__ weights,
                                  float* __restrict__ ws) {
    int t = threadIdx.x;
    if (t < 32) {
        // phase tables for layers 0,1 (0.25 folds the H-layer normalization)
        int l = t >> 4, idx = t & 15;
        float ang = layer_angle(weights, l, idx);
        ws[l * 32 + idx]      = 0.25f * __cosf(ang);
        ws[l * 32 + 16 + idx] = 0.25f * __sinf(ang);
    } else if (t < 64) {
        // pair coefficients for the folded final layer (pure phase, factor 2)
        int e = t - 32;            // 0..31
        int w = e >> 3, p = e & 7;
        int m = 8 >> w;
        int j = ((p & ~(m - 1)) << 1) | (p & (m - 1));  // p-th idx with bit m clear
        int k = j | m;
        float dA = layer_angle(weights, 2, j) - layer_angle(weights, 2, k);
        ws[64 + e * 2]     = 2.f * __cosf(dA);
        ws[64 + e * 2 + 1] = 2.f * __sinf(dA);
    }
}

__device__ __forceinline__ void bfly(float v[16], int m) {
    #pragma unroll
    for (int i = 0; i < 16; ++i) {
        if (!(i & m)) {
            int j = i | m;
            float a = v[i], b = v[j];
            v[i] = a + b;
            v[j] = a - b;
        }
    }
}

__global__ __launch_bounds__(256) void qcircuit_kernel(
    const float* __restrict__ x,
    const float* __restrict__ lin_w,
    const float* __restrict__ lin_b,
    const float* __restrict__ ws,
    float* __restrict__ out,
    int nthreads)
{
    int t = blockIdx.x * blockDim.x + threadIdx.x;
    if (t >= nthreads) return;
    int b = t >> 2;
    int s = t & 3;

    // angle gather: xv = x.reshape(b,2,2,2,2).transpose(0,1,3,2,4)
    const float* xr = x + (size_t)b * 16;
    int base = ((s >> 1) << 3) + ((s & 1) << 1);
    float2 q0 = *(const float2*)(xr + base);       // angles 0,1
    float2 q1 = *(const float2*)(xr + base + 4);   // angles 2,3

    float c0, s0, c1, s1, c2, s2, c3, s3;
    __sincosf(0.5f * q0.x, &s0, &c0);
    __sincosf(0.5f * q0.y, &s1, &c1);
    __sincosf(0.5f * q1.x, &s2, &c2);
    __sincosf(0.5f * q1.y, &s3, &c3);

    // product-state amplitudes: amp[idx] = w01[idx>>2] * w23[idx&3]
    float w01[4] = {c0 * c1, c0 * s1, s0 * c1, s0 * s1};
    float w23[4] = {c2 * c3, c2 * s3, s2 * c3, s2 * s3};

    float re[16], im[16];

    // layer 0: diagonal phase (batch-uniform, via SGPR loads) on real state
    #pragma unroll
    for (int i = 0; i < 16; ++i) {
        float a = w01[i >> 2] * w23[i & 3];
        re[i] = a * ws[i];
        im[i] = a * ws[16 + i];
    }
    bfly(re, 8); bfly(re, 4); bfly(re, 2); bfly(re, 1);
    bfly(im, 8); bfly(im, 4); bfly(im, 2); bfly(im, 1);

    // layer 1: complex diagonal + butterfly
    #pragma unroll
    for (int i = 0; i < 16; ++i) {
        float dc = ws[32 + i], ds = ws[48 + i];
        float r = re[i] * dc - im[i] * ds;
        float m = re[i] * ds + im[i] * dc;
        re[i] = r; im[i] = m;
    }
    bfly(re, 8); bfly(re, 4); bfly(re, 2); bfly(re, 1);
    bfly(im, 8); bfly(im, 4); bfly(im, 2); bfly(im, 1);

    // folded final layer: z_w from Hermitian pair products
    float z[4];
    int cidx = 0;
    #pragma unroll
    for (int w = 0; w < 4; ++w) {
        int m = 8 >> w;
        float zz = 0.f;
        #pragma unroll
        for (int j = 0; j < 16; ++j) {
            if (!(j & m)) {
                int k = j | m;
                float pre = re[j] * re[k] + im[j] * im[k];
                float pim = im[j] * re[k] - re[j] * im[k];
                float cr = ws[64 + cidx * 2], ci = ws[64 + cidx * 2 + 1];
                zz += cr * pre;
                zz -= ci * pim;
                ++cidx;
            }
        }
        z[w] = zz;
    }

    // partial logits: feature block j = s*4 + w
    float4 wa = *(const float4*)(lin_w + s * 4);
    float4 wb = *(const float4*)(lin_w + 16 + s * 4);
    float l0 = z[0] * wa.x + z[1] * wa.y + z[2] * wa.z + z[3] * wa.w;
    float l1 = z[0] * wb.x + z[1] * wb.y + z[2] * wb.z + z[3] * wb.w;

    // reduce across the 4 lanes of this batch row
    l0 += __shfl_xor(l0, 1); l0 += __shfl_xor(l0, 2);
    l1 += __shfl_xor(l1, 1); l1 += __shfl_xor(l1, 2);

    if (s == 0) {
        l0 += lin_b[0];
        l1 += lin_b[1];
        float m = fmaxf(l0, l1);
        float e0 = __expf(l0 - m), e1 = __expf(l1 - m);
        float inv = 1.f / (e0 + e1);
        *(float2*)(out + (size_t)b * 2) = make_float2(e0 * inv, e1 * inv);
    }
}

extern "C" void kernel_launch(void* const* d_in, const int* in_sizes, int n_in,
                              void* d_out, int out_size, void* d_ws, size_t ws_size,
                              hipStream_t stream) {
    const float* x       = (const float*)d_in[0];
    const float* weights = (const float*)d_in[1];
    const float* lin_w   = (const float*)d_in[2];
    const float* lin_b   = (const float*)d_in[3];
    float* out = (float*)d_out;
    float* ws  = (float*)d_ws;

    int bsz = in_sizes[0] / 16;
    int nthreads = bsz * 4;

    precompute_tables<<<1, 64, 0, stream>>>(weights, ws);

    int block = 256;
    int grid = (nthreads + block - 1) / block;
    qcircuit_kernel<<<grid, block, 0, stream>>>(x, lin_w, lin_b, ws, out, nthreads);
}